// Round 2
// baseline (4399.240 us; speedup 1.0000x reference)
//
#include <hip/hip_runtime.h>

// Problem constants (fixed by reference)
#define NTOK   8192
#define HIDDEN 2048
#define NHEAD  32
#define HDIM   64
#define BLK    256
#define NBLK   32          // NTOK / BLK
#define QKVW   6144        // 3 * HIDDEN

// slope[h] = 2^(-0.25*(h+1)) * (1 - 0/79 + 1e-5)
__device__ __forceinline__ float head_slope(int h) {
    return exp2f(-0.25f * (float)(h + 1)) * 1.00001f;
}

// bf16 storage helpers (avoid hip_bf16 header portability issues)
__device__ __forceinline__ unsigned short f2bf(float x) {
    unsigned int u = __float_as_uint(x);
    unsigned int r = (u + 0x7FFFu + ((u >> 16) & 1u)) >> 16;   // RNE
    return (unsigned short)r;
}
__device__ __forceinline__ float bf2f(unsigned short x) {
    return __uint_as_float(((unsigned int)x) << 16);
}

__device__ __forceinline__ float4 load4(const float* p) { return *(const float4*)p; }
__device__ __forceinline__ float4 load4(const unsigned short* p) {
    ushort4 u = *(const ushort4*)p;
    return make_float4(bf2f(u.x), bf2f(u.y), bf2f(u.z), bf2f(u.w));
}
__device__ __forceinline__ void store4(float* p, float4 v) { *(float4*)p = v; }
__device__ __forceinline__ void store4(unsigned short* p, float4 v) {
    ushort4 u = {f2bf(v.x), f2bf(v.y), f2bf(v.z), f2bf(v.w)};
    *(ushort4*)p = u;
}

// ---------------------------------------------------------------------------
// Tiled fp32 SGEMM: C[M,N] = epi(A[M,K] @ B[N,K]^T)
// BM=BN=128, BK=16, 256 threads, 8x8 outputs/thread in 4 quadrant 4x4 tiles.
// EPI: 0 = silu(x), 1 = x, 2 = sigmoid(x) * Mul[idx]
// ---------------------------------------------------------------------------
template <int EPI, typename OutT>
__global__ __launch_bounds__(256, 2) void sgemm_bt(
    const float* __restrict__ A, const float* __restrict__ B,
    OutT* __restrict__ C, const float* __restrict__ Mul,
    int M, int Ncol, int K) {
    __shared__ __align__(16) float As[16][132];
    __shared__ __align__(16) float Bs[16][132];

    const int t  = threadIdx.x;
    const int bm = blockIdx.y, bn = blockIdx.x;
    const int tx = t & 15, ty = t >> 4;      // 16x16 thread grid
    const int lr = t >> 2;                   // load row 0..63 (and +64)
    const int lc = (t & 3) << 2;             // load col 0,4,8,12

    const float* Ap = A + ((long)(bm * 128 + lr)) * K + lc;
    const float* Bp = B + ((long)(bn * 128 + lr)) * K + lc;
    const long rowK64 = (long)64 * K;

    float acc[4][4][4];                      // [quad][i][j]
#pragma unroll
    for (int q = 0; q < 4; q++)
#pragma unroll
        for (int i = 0; i < 4; i++)
#pragma unroll
            for (int j = 0; j < 4; j++) acc[q][i][j] = 0.f;

    for (int k0 = 0; k0 < K; k0 += 16) {
        float4 a0 = *(const float4*)(Ap + k0);
        float4 a1 = *(const float4*)(Ap + rowK64 + k0);
        float4 b0 = *(const float4*)(Bp + k0);
        float4 b1 = *(const float4*)(Bp + rowK64 + k0);
        __syncthreads();
        As[lc + 0][lr] = a0.x; As[lc + 1][lr] = a0.y;
        As[lc + 2][lr] = a0.z; As[lc + 3][lr] = a0.w;
        As[lc + 0][64 + lr] = a1.x; As[lc + 1][64 + lr] = a1.y;
        As[lc + 2][64 + lr] = a1.z; As[lc + 3][64 + lr] = a1.w;
        Bs[lc + 0][lr] = b0.x; Bs[lc + 1][lr] = b0.y;
        Bs[lc + 2][lr] = b0.z; Bs[lc + 3][lr] = b0.w;
        Bs[lc + 0][64 + lr] = b1.x; Bs[lc + 1][64 + lr] = b1.y;
        Bs[lc + 2][64 + lr] = b1.z; Bs[lc + 3][64 + lr] = b1.w;
        __syncthreads();
#pragma unroll
        for (int kk = 0; kk < 16; kk++) {
            float4 af0 = *(const float4*)&As[kk][ty << 2];
            float4 af1 = *(const float4*)&As[kk][64 + (ty << 2)];
            float4 bf0 = *(const float4*)&Bs[kk][tx << 2];
            float4 bf1 = *(const float4*)&Bs[kk][64 + (tx << 2)];
            float a_[8] = {af0.x, af0.y, af0.z, af0.w, af1.x, af1.y, af1.z, af1.w};
            float b_[8] = {bf0.x, bf0.y, bf0.z, bf0.w, bf1.x, bf1.y, bf1.z, bf1.w};
#pragma unroll
            for (int i = 0; i < 4; i++)
#pragma unroll
                for (int j = 0; j < 4; j++) {
                    acc[0][i][j] += a_[i] * b_[j];
                    acc[1][i][j] += a_[i] * b_[4 + j];
                    acc[2][i][j] += a_[4 + i] * b_[j];
                    acc[3][i][j] += a_[4 + i] * b_[4 + j];
                }
        }
    }

    // epilogue
#pragma unroll
    for (int qr = 0; qr < 2; qr++)
#pragma unroll
        for (int qc = 0; qc < 2; qc++)
#pragma unroll
            for (int i = 0; i < 4; i++) {
                long row = (long)bm * 128 + qr * 64 + (ty << 2) + i;
                long col = (long)bn * 128 + qc * 64 + (tx << 2);
                long idx = row * Ncol + col;
                float* ap = acc[qr * 2 + qc][i];
                float4 o;
                if (EPI == 0) {                    // silu
                    o.x = ap[0] / (1.f + expf(-ap[0]));
                    o.y = ap[1] / (1.f + expf(-ap[1]));
                    o.z = ap[2] / (1.f + expf(-ap[2]));
                    o.w = ap[3] / (1.f + expf(-ap[3]));
                } else if (EPI == 1) {             // plain
                    o.x = ap[0]; o.y = ap[1]; o.z = ap[2]; o.w = ap[3];
                } else {                           // sigmoid(acc) * Mul
                    float4 m = *(const float4*)(Mul + idx);
                    o.x = m.x / (1.f + expf(-ap[0]));
                    o.y = m.y / (1.f + expf(-ap[1]));
                    o.z = m.z / (1.f + expf(-ap[2]));
                    o.w = m.w / (1.f + expf(-ap[3]));
                }
                store4(C + idx, o);
            }
}

// ---------------------------------------------------------------------------
// contrib[h][b][d][e] = sum_n k_decay[n] * k[n][d] * v[n][e]   (per head,block)
// grid (NBLK, NHEAD), 256 threads, 4x4 outputs/thread over 64x64.
// ---------------------------------------------------------------------------
template <typename T>
__global__ __launch_bounds__(256) void attn_contrib(
    const T* __restrict__ qkv, float* __restrict__ contrib) {
    const int b = blockIdx.x, h = blockIdx.y;
    const float s = head_slope(h);
    __shared__ __align__(16) float ks[64][68];   // k (pre-scaled by k_decay)
    __shared__ __align__(16) float vs[64][68];
    const int t = threadIdx.x, tx = t & 15, ty = t >> 4;
    const T* base = qkv + (long)(b * BLK) * QKVW + h * (3 * HDIM);

    float acc[4][4];
#pragma unroll
    for (int i = 0; i < 4; i++)
#pragma unroll
        for (int j = 0; j < 4; j++) acc[i][j] = 0.f;

    for (int nt = 0; nt < 4; nt++) {
        __syncthreads();
#pragma unroll
        for (int i = 0; i < 4; i++) {
            int idx = t + 256 * i;               // 0..1023
            int n   = idx >> 4;                  // 0..63
            int c   = (idx & 15) << 2;           // 0..60
            int tok = nt * 64 + n;               // block-local token
            float kd = expf(-s * (float)(BLK - 1 - tok));
            float4 k4 = load4(base + (long)tok * QKVW + HDIM + c);
            float4 v4 = load4(base + (long)tok * QKVW + 2 * HDIM + c);
            k4.x *= kd; k4.y *= kd; k4.z *= kd; k4.w *= kd;
            *(float4*)&ks[n][c] = k4;
            *(float4*)&vs[n][c] = v4;
        }
        __syncthreads();
#pragma unroll 8
        for (int nn = 0; nn < 64; nn++) {
            float4 av = *(const float4*)&ks[nn][ty << 2];
            float4 bv = *(const float4*)&vs[nn][tx << 2];
            float a_[4] = {av.x, av.y, av.z, av.w};
            float b_[4] = {bv.x, bv.y, bv.z, bv.w};
#pragma unroll
            for (int i = 0; i < 4; i++)
#pragma unroll
                for (int j = 0; j < 4; j++) acc[i][j] += a_[i] * b_[j];
        }
    }
    float* out = contrib + ((long)(h * NBLK + b)) * 4096;
#pragma unroll
    for (int i = 0; i < 4; i++) {
        float4 o = {acc[i][0], acc[i][1], acc[i][2], acc[i][3]};
        *(float4*)(out + ((ty << 2) + i) * 64 + (tx << 2)) = o;
    }
}

// ---------------------------------------------------------------------------
// Sequential decay scan over blocks: states[h][b] = state BEFORE block b.
// In-place safe (states may alias contrib): contrib read into regs first.
// grid NHEAD, 256 threads (16 state elements each, coalesced stride-256).
// ---------------------------------------------------------------------------
__global__ __launch_bounds__(256) void attn_scan(
    const float* __restrict__ kv0, const float* __restrict__ contrib,
    float* __restrict__ states) {
    const int h = blockIdx.x, t = threadIdx.x;
    const float s  = head_slope(h);
    const float bd = expf(-s * (float)BLK);
    float st[16], c[16];
    const float* kvp = kv0 + (long)h * 4096;
#pragma unroll
    for (int i = 0; i < 16; i++) st[i] = kvp[t + 256 * i];
    for (int b = 0; b < NBLK; b++) {
        const float* cp = contrib + ((long)(h * NBLK + b)) * 4096;
        float* sp = states + ((long)(h * NBLK + b)) * 4096;
#pragma unroll
        for (int i = 0; i < 16; i++) c[i] = cp[t + 256 * i];
#pragma unroll
        for (int i = 0; i < 16; i++) sp[t + 256 * i] = st[i];
#pragma unroll
        for (int i = 0; i < 16; i++) st[i] = bd * st[i] + c[i];
    }
}

// ---------------------------------------------------------------------------
// Main attention per (head, block):
//   out = diag(q_decay) * (q @ state) + ((q @ k^T) .* diag_decay) @ v
// 64-row q chunks; causal tile skip; writes hidden[n, h*64+e] (row-major 2048).
// ---------------------------------------------------------------------------
template <typename T>
__global__ __launch_bounds__(256) void attn_intra(
    const T* __restrict__ qkv, const float* __restrict__ states,
    float* __restrict__ hidden) {
    const int b = blockIdx.x, h = blockIdx.y;
    const float s = head_slope(h);
    __shared__ __align__(16) float qT[64][68];   // q chunk, [d][m]
    __shared__ __align__(16) float stS[64][68];  // kv state, [d][e]
    __shared__ __align__(16) float kvT[64][68];  // k tile [d][n], then v tile [n][e]
    __shared__ __align__(16) float sT[64][68];   // S tile, [n][m]
    const int t = threadIdx.x, tx = t & 15, ty = t >> 4;
    const T* base = qkv + (long)(b * BLK) * QKVW + h * (3 * HDIM);

    {   // load state once (natural layout)
        const float* sp = states + ((long)(h * NBLK + b)) * 4096;
#pragma unroll
        for (int i = 0; i < 4; i++) {
            int idx = t + 256 * i;
            int d = idx >> 4, c = (idx & 15) << 2;
            *(float4*)&stS[d][c] = *(const float4*)(sp + d * 64 + c);
        }
    }

    for (int r0 = 0; r0 < BLK; r0 += 64) {
        __syncthreads();  // protect qT (prev chunk) / stS (first iter)
#pragma unroll
        for (int i = 0; i < 4; i++) {            // q chunk, transposed store
            int idx = t + 256 * i;
            int m = idx >> 4, c = (idx & 15) << 2;
            float4 q4 = load4(base + (long)(r0 + m) * QKVW + c);
            qT[c + 0][m] = q4.x; qT[c + 1][m] = q4.y;
            qT[c + 2][m] = q4.z; qT[c + 3][m] = q4.w;
        }
        __syncthreads();

        float acc[4][4];
#pragma unroll
        for (int i = 0; i < 4; i++)
#pragma unroll
            for (int j = 0; j < 4; j++) acc[i][j] = 0.f;

        // inter = q @ state  (row-decay applied after)
#pragma unroll 8
        for (int dd = 0; dd < 64; dd++) {
            float4 av = *(const float4*)&qT[dd][ty << 2];
            float4 bv = *(const float4*)&stS[dd][tx << 2];
            float a_[4] = {av.x, av.y, av.z, av.w};
            float b_[4] = {bv.x, bv.y, bv.z, bv.w};
#pragma unroll
            for (int i = 0; i < 4; i++)
#pragma unroll
                for (int j = 0; j < 4; j++) acc[i][j] += a_[i] * b_[j];
        }
#pragma unroll
        for (int i = 0; i < 4; i++) {
            float qd = expf(-s * (float)(r0 + (ty << 2) + i + 1));
#pragma unroll
            for (int j = 0; j < 4; j++) acc[i][j] *= qd;
        }

        const int ntmax = r0 >> 6;               // causal tile skip
        for (int nt = 0; nt <= ntmax; nt++) {
            const int n0 = nt * 64;
            __syncthreads();                     // prev intra reads of kvT/sT done
#pragma unroll
            for (int i = 0; i < 4; i++) {        // k tile, transposed
                int idx = t + 256 * i;
                int n = idx >> 4, c = (idx & 15) << 2;
                float4 k4 = load4(base + (long)(n0 + n) * QKVW + HDIM + c);
                kvT[c + 0][n] = k4.x; kvT[c + 1][n] = k4.y;
                kvT[c + 2][n] = k4.z; kvT[c + 3][n] = k4.w;
            }
            __syncthreads();

            float sacc[4][4];
#pragma unroll
            for (int i = 0; i < 4; i++)
#pragma unroll
                for (int j = 0; j < 4; j++) sacc[i][j] = 0.f;
#pragma unroll 8
            for (int dd = 0; dd < 64; dd++) {    // S = q @ k^T
                float4 av = *(const float4*)&qT[dd][ty << 2];
                float4 bv = *(const float4*)&kvT[dd][tx << 2];
                float a_[4] = {av.x, av.y, av.z, av.w};
                float b_[4] = {bv.x, bv.y, bv.z, bv.w};
#pragma unroll
                for (int i = 0; i < 4; i++)
#pragma unroll
                    for (int j = 0; j < 4; j++) sacc[i][j] += a_[i] * b_[j];
            }
            __syncthreads();                     // kvT reads done -> can overwrite

            // decayed S (transposed store) + v tile into kvT (natural)
#pragma unroll
            for (int i = 0; i < 4; i++)
#pragma unroll
                for (int j = 0; j < 4; j++) {
                    int m = r0 + (ty << 2) + i;  // block-local row
                    int n = n0 + (tx << 2) + j;  // block-local col
                    float dm = (m >= n) ? expf(-s * (float)(m - n)) : 0.f;
                    sT[(tx << 2) + j][(ty << 2) + i] = sacc[i][j] * dm;
                }
#pragma unroll
            for (int i = 0; i < 4; i++) {
                int idx = t + 256 * i;
                int n = idx >> 4, c = (idx & 15) << 2;
                float4 v4 = load4(base + (long)(n0 + n) * QKVW + 2 * HDIM + c);
                *(float4*)&kvT[n][c] = v4;
            }
            __syncthreads();
#pragma unroll 8
            for (int nn = 0; nn < 64; nn++) {    // intra: acc += S @ v
                float4 av = *(const float4*)&sT[nn][ty << 2];
                float4 bv = *(const float4*)&kvT[nn][tx << 2];
                float a_[4] = {av.x, av.y, av.z, av.w};
                float b_[4] = {bv.x, bv.y, bv.z, bv.w};
#pragma unroll
                for (int i = 0; i < 4; i++)
#pragma unroll
                    for (int j = 0; j < 4; j++) acc[i][j] += a_[i] * b_[j];
            }
        }

        float* hp = hidden + ((long)(b * BLK + r0 + (ty << 2))) * HIDDEN +
                    h * HDIM + (tx << 2);
#pragma unroll
        for (int i = 0; i < 4; i++) {
            float4 o = {acc[i][0], acc[i][1], acc[i][2], acc[i][3]};
            *(float4*)(hp + (long)i * HIDDEN) = o;
        }
    }
}

// ---------------------------------------------------------------------------
// RMSNorm over rows of hidden (in place). grid NTOK, 256 threads.
// ---------------------------------------------------------------------------
__global__ __launch_bounds__(256) void rmsnorm_rows(
    float* __restrict__ hidden, const float* __restrict__ w) {
    const int row = blockIdx.x, t = threadIdx.x;
    float* hp = hidden + (long)row * HIDDEN;
    float4 a = *(const float4*)(hp + (t << 2));
    float4 b = *(const float4*)(hp + 1024 + (t << 2));
    float ss = a.x * a.x + a.y * a.y + a.z * a.z + a.w * a.w +
               b.x * b.x + b.y * b.y + b.z * b.z + b.w * b.w;
#pragma unroll
    for (int off = 32; off > 0; off >>= 1) ss += __shfl_down(ss, off);
    __shared__ float red[4];
    if ((t & 63) == 0) red[t >> 6] = ss;
    __syncthreads();
    float tot = red[0] + red[1] + red[2] + red[3];
    float scale = rsqrtf(tot * (1.f / HIDDEN) + 1e-5f);
    float4 wa = *(const float4*)(w + (t << 2));
    float4 wb = *(const float4*)(w + 1024 + (t << 2));
    a.x *= scale * wa.x; a.y *= scale * wa.y; a.z *= scale * wa.z; a.w *= scale * wa.w;
    b.x *= scale * wb.x; b.y *= scale * wb.y; b.z *= scale * wb.z; b.w *= scale * wb.w;
    *(float4*)(hp + (t << 2)) = a;
    *(float4*)(hp + 1024 + (t << 2)) = b;
}

// ---------------------------------------------------------------------------
extern "C" void kernel_launch(void* const* d_in, const int* in_sizes, int n_in,
                              void* d_out, int out_size, void* d_ws, size_t ws_size,
                              hipStream_t stream) {
    (void)in_sizes; (void)n_in; (void)out_size;
    const float* hs   = (const float*)d_in[0];   // (8192, 2048)
    const float* kv0  = (const float*)d_in[1];   // (32, 64, 64)
    const float* Wqkv = (const float*)d_in[2];   // (6144, 2048)
    const float* Wg   = (const float*)d_in[3];   // (2048, 2048)
    const float* Wo   = (const float*)d_in[4];   // (2048, 2048)
    const float* nw   = (const float*)d_in[5];   // (2048,)
    float* out = (float*)d_out;                  // hidden lives here pre-gate

    const size_t QKV_ELEMS = (size_t)NTOK * QKVW;         // 50,331,648
    const size_t CS_ELEMS  = (size_t)NHEAD * NBLK * 4096; //  4,194,304
    const size_t needA = (QKV_ELEMS + CS_ELEMS) * sizeof(float);     // 208 MiB

    if (ws_size >= needA) {
        // ---- PATH A: fp32 qkv ----
        float* qkv   = (float*)d_ws;
        float* cs    = qkv + QKV_ELEMS;           // contrib, then states in-place
        float* gated = qkv;                       // reuse qkv region after attn

        sgemm_bt<0, float><<<dim3(QKVW / 128, NTOK / 128), 256, 0, stream>>>(
            hs, Wqkv, qkv, nullptr, NTOK, QKVW, HIDDEN);
        attn_contrib<float><<<dim3(NBLK, NHEAD), 256, 0, stream>>>(qkv, cs);
        attn_scan<<<NHEAD, 256, 0, stream>>>(kv0, cs, cs);
        attn_intra<float><<<dim3(NBLK, NHEAD), 256, 0, stream>>>(qkv, cs, out);
        rmsnorm_rows<<<NTOK, 256, 0, stream>>>(out, nw);
        sgemm_bt<2, float><<<dim3(HIDDEN / 128, NTOK / 128), 256, 0, stream>>>(
            hs, Wg, gated, out, NTOK, HIDDEN, HIDDEN);
        sgemm_bt<1, float><<<dim3(HIDDEN / 128, NTOK / 128), 256, 0, stream>>>(
            gated, Wo, out, nullptr, NTOK, HIDDEN, HIDDEN);
    } else {
        // ---- PATH B: bf16 qkv (112 MiB ws) ----
        unsigned short* qkvh = (unsigned short*)d_ws;
        float* cs    = (float*)((char*)d_ws + QKV_ELEMS * sizeof(unsigned short));
        float* gated = (float*)d_ws;              // reuse qkv region after attn

        sgemm_bt<0, unsigned short><<<dim3(QKVW / 128, NTOK / 128), 256, 0, stream>>>(
            hs, Wqkv, qkvh, nullptr, NTOK, QKVW, HIDDEN);
        attn_contrib<unsigned short><<<dim3(NBLK, NHEAD), 256, 0, stream>>>(qkvh, cs);
        attn_scan<<<NHEAD, 256, 0, stream>>>(kv0, cs, cs);
        attn_intra<unsigned short><<<dim3(NBLK, NHEAD), 256, 0, stream>>>(qkvh, cs, out);
        rmsnorm_rows<<<NTOK, 256, 0, stream>>>(out, nw);
        sgemm_bt<2, float><<<dim3(HIDDEN / 128, NTOK / 128), 256, 0, stream>>>(
            hs, Wg, gated, out, NTOK, HIDDEN, HIDDEN);
        sgemm_bt<1, float><<<dim3(HIDDEN / 128, NTOK / 128), 256, 0, stream>>>(
            gated, Wo, out, nullptr, NTOK, HIDDEN, HIDDEN);
    }
}

// Round 3
// 984.431 us; speedup vs baseline: 4.4688x; 4.4688x over previous
//
#include <hip/hip_runtime.h>

// Problem constants (fixed by reference)
#define NTOK   8192
#define HIDDEN 2048
#define NHEAD  32
#define HDIM   64
#define BLK    256
#define NBLK   32          // NTOK / BLK
#define QKVW   6144        // 3 * HIDDEN

typedef unsigned short ushort_t;
typedef __attribute__((ext_vector_type(8))) short bf16x8;   // 8 bf16 = 4 VGPRs
typedef __attribute__((ext_vector_type(4))) float floatx4;  // MFMA C/D

// slope[h] = 2^(-0.25*(h+1)) * (1 - 0/79 + 1e-5)
__device__ __forceinline__ float head_slope(int h) {
    return exp2f(-0.25f * (float)(h + 1)) * 1.00001f;
}

// bf16 helpers
__device__ __forceinline__ ushort_t f2bf(float x) {
    unsigned int u = __float_as_uint(x);
    unsigned int r = (u + 0x7FFFu + ((u >> 16) & 1u)) >> 16;   // RNE
    return (ushort_t)r;
}
__device__ __forceinline__ float bf2f(ushort_t x) {
    return __uint_as_float(((unsigned int)x) << 16);
}
__device__ __forceinline__ float4 load4(const float* p) { return *(const float4*)p; }
__device__ __forceinline__ float4 load4(const ushort_t* p) {
    ushort4 u = *(const ushort4*)p;
    return make_float4(bf2f(u.x), bf2f(u.y), bf2f(u.z), bf2f(u.w));
}
__device__ __forceinline__ void store1(float* p, float v) { *p = v; }
__device__ __forceinline__ void store1(ushort_t* p, float v) { *p = f2bf(v); }

// async global->LDS, 16B per lane (lds dest = wave-uniform base + lane*16)
#define GLOAD_LDS16(g, l)                                              \
    __builtin_amdgcn_global_load_lds(                                  \
        (const __attribute__((address_space(1))) void*)(g),            \
        (__attribute__((address_space(3))) void*)(l), 16, 0, 0)

// ---------------------------------------------------------------------------
// fp32 -> bf16 convert, 8 elems/thread. n8 = n/8.
// ---------------------------------------------------------------------------
__global__ __launch_bounds__(256) void cvt_bf16(
    const float* __restrict__ in, ushort_t* __restrict__ out, int n8) {
    int i = blockIdx.x * 256 + threadIdx.x;
    if (i >= n8) return;
    long base = (long)i * 8;
    float4 a = *(const float4*)(in + base);
    float4 b = *(const float4*)(in + base + 4);
    ushort4 u0 = {f2bf(a.x), f2bf(a.y), f2bf(a.z), f2bf(a.w)};
    ushort4 u1 = {f2bf(b.x), f2bf(b.y), f2bf(b.z), f2bf(b.w)};
    *(ushort4*)(out + base) = u0;
    *(ushort4*)(out + base + 4) = u1;
}

// ---------------------------------------------------------------------------
// bf16 MFMA GEMM: C[M,N] = epi(A[M,K] @ B[N,K]^T), fp32 accumulate.
// 128x128 tile, BK=32, 256 threads = 4 waves (2x2), each wave 64x64 via
// 4x4 grid of 16x16x32 MFMAs. m97 structure: global_load_lds width=16 into
// contiguous [row][32] bf16 LDS (no padding - required by load_lds), then
// ds_read_b128 fragments. EPI: 0=silu, 1=plain, 2=sigmoid(x)*Mul[idx].
// ---------------------------------------------------------------------------
template <int EPI, typename OutT>
__global__ __launch_bounds__(256) void gemm_bt_bf16(
    const ushort_t* __restrict__ A, const ushort_t* __restrict__ B,
    OutT* __restrict__ C, const float* __restrict__ Mul,
    int M, int Ncol, int K) {
    __shared__ ushort_t Al[128 * 32];   // [row][k], 64B rows
    __shared__ ushort_t Bl[128 * 32];

    const int t = threadIdx.x;
    const int wave = t >> 6, lane = t & 63;
    const int bm = blockIdx.y, bn = blockIdx.x;
    const int wm = (wave >> 1) * 64;    // wave row offset in 128-tile
    const int wn = (wave & 1) * 64;     // wave col offset

    // staging: lane -> (row in 16-row group, 16B chunk); 4 issues/wave
    const int srow = lane >> 2;          // 0..15
    const int scol = (lane & 3) * 8;     // bf16 col 0,8,16,24
    const ushort_t* Ag0 = A + ((long)(bm * 128 + wave * 16 + srow)) * K + scol;
    const ushort_t* Ag1 = Ag0 + (long)64 * K;
    const ushort_t* Bg0 = B + ((long)(bn * 128 + wave * 16 + srow)) * K + scol;
    const ushort_t* Bg1 = Bg0 + (long)64 * K;
    ushort_t* Al0 = &Al[(wave * 16) * 32];
    ushort_t* Al1 = &Al[(wave * 16 + 64) * 32];
    ushort_t* Bl0 = &Bl[(wave * 16) * 32];
    ushort_t* Bl1 = &Bl[(wave * 16 + 64) * 32];

    // fragment read coords: A[m=lane&15][k=(lane>>4)*8+j], B same (B^T input)
    const int fm = lane & 15;
    const int fk = (lane >> 4) * 8;

    floatx4 acc[4][4];                   // [mt][nt]
#pragma unroll
    for (int i = 0; i < 4; i++)
#pragma unroll
        for (int j = 0; j < 4; j++) acc[i][j] = (floatx4){0.f, 0.f, 0.f, 0.f};

    for (int k0 = 0; k0 < K; k0 += 32) {
        GLOAD_LDS16(Ag0 + k0, Al0);
        GLOAD_LDS16(Ag1 + k0, Al1);
        GLOAD_LDS16(Bg0 + k0, Bl0);
        GLOAD_LDS16(Bg1 + k0, Bl1);
        __syncthreads();                 // drains vmcnt (load_lds) + barrier

        bf16x8 af[4], bf[4];
#pragma unroll
        for (int mt = 0; mt < 4; mt++)
            af[mt] = *(const bf16x8*)&Al[(wm + mt * 16 + fm) * 32 + fk];
#pragma unroll
        for (int nt = 0; nt < 4; nt++)
            bf[nt] = *(const bf16x8*)&Bl[(wn + nt * 16 + fm) * 32 + fk];
#pragma unroll
        for (int mt = 0; mt < 4; mt++)
#pragma unroll
            for (int nt = 0; nt < 4; nt++)
                acc[mt][nt] = __builtin_amdgcn_mfma_f32_16x16x32_bf16(
                    af[mt], bf[nt], acc[mt][nt], 0, 0, 0);
        __syncthreads();                 // LDS reads done before next stage
    }

    // epilogue: C/D layout col=lane&15, row=(lane>>4)*4+reg
    const int cq = lane >> 4;
#pragma unroll
    for (int mt = 0; mt < 4; mt++)
#pragma unroll
        for (int nt = 0; nt < 4; nt++) {
            long col = (long)bn * 128 + wn + nt * 16 + fm;
#pragma unroll
            for (int r = 0; r < 4; r++) {
                long row = (long)bm * 128 + wm + mt * 16 + cq * 4 + r;
                long idx = row * Ncol + col;
                float x = acc[mt][nt][r];
                float o;
                if (EPI == 0)      o = x / (1.f + expf(-x));          // silu
                else if (EPI == 1) o = x;                             // plain
                else               o = Mul[idx] / (1.f + expf(-x));   // gate
                store1(C + idx, o);
            }
        }
}

// ---------------------------------------------------------------------------
// contrib[h][b][d][e] = sum_n k_decay[n] * k[n][d] * v[n][e]   (per head,block)
// ---------------------------------------------------------------------------
template <typename T>
__global__ __launch_bounds__(256) void attn_contrib(
    const T* __restrict__ qkv, float* __restrict__ contrib) {
    const int b = blockIdx.x, h = blockIdx.y;
    const float s = head_slope(h);
    __shared__ __align__(16) float ks[64][68];
    __shared__ __align__(16) float vs[64][68];
    const int t = threadIdx.x, tx = t & 15, ty = t >> 4;
    const T* base = qkv + (long)(b * BLK) * QKVW + h * (3 * HDIM);

    float acc[4][4];
#pragma unroll
    for (int i = 0; i < 4; i++)
#pragma unroll
        for (int j = 0; j < 4; j++) acc[i][j] = 0.f;

    for (int nt = 0; nt < 4; nt++) {
        __syncthreads();
#pragma unroll
        for (int i = 0; i < 4; i++) {
            int idx = t + 256 * i;
            int n = idx >> 4, c = (idx & 15) << 2;
            int tok = nt * 64 + n;
            float kd = expf(-s * (float)(BLK - 1 - tok));
            float4 k4 = load4(base + (long)tok * QKVW + HDIM + c);
            float4 v4 = load4(base + (long)tok * QKVW + 2 * HDIM + c);
            k4.x *= kd; k4.y *= kd; k4.z *= kd; k4.w *= kd;
            *(float4*)&ks[n][c] = k4;
            *(float4*)&vs[n][c] = v4;
        }
        __syncthreads();
#pragma unroll 8
        for (int nn = 0; nn < 64; nn++) {
            float4 av = *(const float4*)&ks[nn][ty << 2];
            float4 bv = *(const float4*)&vs[nn][tx << 2];
            float a_[4] = {av.x, av.y, av.z, av.w};
            float b_[4] = {bv.x, bv.y, bv.z, bv.w};
#pragma unroll
            for (int i = 0; i < 4; i++)
#pragma unroll
                for (int j = 0; j < 4; j++) acc[i][j] += a_[i] * b_[j];
        }
    }
    float* out = contrib + ((long)(h * NBLK + b)) * 4096;
#pragma unroll
    for (int i = 0; i < 4; i++) {
        float4 o = {acc[i][0], acc[i][1], acc[i][2], acc[i][3]};
        *(float4*)(out + ((ty << 2) + i) * 64 + (tx << 2)) = o;
    }
}

// ---------------------------------------------------------------------------
// Sequential decay scan over blocks (in-place safe).
// ---------------------------------------------------------------------------
__global__ __launch_bounds__(256) void attn_scan(
    const float* __restrict__ kv0, const float* __restrict__ contrib,
    float* __restrict__ states) {
    const int h = blockIdx.x, t = threadIdx.x;
    const float s  = head_slope(h);
    const float bd = expf(-s * (float)BLK);
    float st[16], c[16];
    const float* kvp = kv0 + (long)h * 4096;
#pragma unroll
    for (int i = 0; i < 16; i++) st[i] = kvp[t + 256 * i];
    for (int b = 0; b < NBLK; b++) {
        const float* cp = contrib + ((long)(h * NBLK + b)) * 4096;
        float* sp = states + ((long)(h * NBLK + b)) * 4096;
#pragma unroll
        for (int i = 0; i < 16; i++) c[i] = cp[t + 256 * i];
#pragma unroll
        for (int i = 0; i < 16; i++) sp[t + 256 * i] = st[i];
#pragma unroll
        for (int i = 0; i < 16; i++) st[i] = bd * st[i] + c[i];
    }
}

// ---------------------------------------------------------------------------
// Main attention per (head, block):
//   out = diag(q_decay)*(q @ state) + ((q @ k^T) .* diag_decay) @ v
// ---------------------------------------------------------------------------
template <typename T>
__global__ __launch_bounds__(256) void attn_intra(
    const T* __restrict__ qkv, const float* __restrict__ states,
    float* __restrict__ hidden) {
    const int b = blockIdx.x, h = blockIdx.y;
    const float s = head_slope(h);
    __shared__ __align__(16) float qT[64][68];
    __shared__ __align__(16) float stS[64][68];
    __shared__ __align__(16) float kvT[64][68];
    __shared__ __align__(16) float sT[64][68];
    const int t = threadIdx.x, tx = t & 15, ty = t >> 4;
    const T* base = qkv + (long)(b * BLK) * QKVW + h * (3 * HDIM);

    {
        const float* sp = states + ((long)(h * NBLK + b)) * 4096;
#pragma unroll
        for (int i = 0; i < 4; i++) {
            int idx = t + 256 * i;
            int d = idx >> 4, c = (idx & 15) << 2;
            *(float4*)&stS[d][c] = *(const float4*)(sp + d * 64 + c);
        }
    }

    for (int r0 = 0; r0 < BLK; r0 += 64) {
        __syncthreads();
#pragma unroll
        for (int i = 0; i < 4; i++) {            // q chunk, transposed store
            int idx = t + 256 * i;
            int m = idx >> 4, c = (idx & 15) << 2;
            float4 q4 = load4(base + (long)(r0 + m) * QKVW + c);
            qT[c + 0][m] = q4.x; qT[c + 1][m] = q4.y;
            qT[c + 2][m] = q4.z; qT[c + 3][m] = q4.w;
        }
        __syncthreads();

        float acc[4][4];
#pragma unroll
        for (int i = 0; i < 4; i++)
#pragma unroll
            for (int j = 0; j < 4; j++) acc[i][j] = 0.f;

#pragma unroll 8
        for (int dd = 0; dd < 64; dd++) {        // inter = q @ state
            float4 av = *(const float4*)&qT[dd][ty << 2];
            float4 bv = *(const float4*)&stS[dd][tx << 2];
            float a_[4] = {av.x, av.y, av.z, av.w};
            float b_[4] = {bv.x, bv.y, bv.z, bv.w};
#pragma unroll
            for (int i = 0; i < 4; i++)
#pragma unroll
                for (int j = 0; j < 4; j++) acc[i][j] += a_[i] * b_[j];
        }
#pragma unroll
        for (int i = 0; i < 4; i++) {
            float qd = expf(-s * (float)(r0 + (ty << 2) + i + 1));
#pragma unroll
            for (int j = 0; j < 4; j++) acc[i][j] *= qd;
        }

        const int ntmax = r0 >> 6;               // causal tile skip
        for (int nt = 0; nt <= ntmax; nt++) {
            const int n0 = nt * 64;
            __syncthreads();
#pragma unroll
            for (int i = 0; i < 4; i++) {        // k tile, transposed
                int idx = t + 256 * i;
                int n = idx >> 4, c = (idx & 15) << 2;
                float4 k4 = load4(base + (long)(n0 + n) * QKVW + HDIM + c);
                kvT[c + 0][n] = k4.x; kvT[c + 1][n] = k4.y;
                kvT[c + 2][n] = k4.z; kvT[c + 3][n] = k4.w;
            }
            __syncthreads();

            float sacc[4][4];
#pragma unroll
            for (int i = 0; i < 4; i++)
#pragma unroll
                for (int j = 0; j < 4; j++) sacc[i][j] = 0.f;
#pragma unroll 8
            for (int dd = 0; dd < 64; dd++) {    // S = q @ k^T
                float4 av = *(const float4*)&qT[dd][ty << 2];
                float4 bv = *(const float4*)&kvT[dd][tx << 2];
                float a_[4] = {av.x, av.y, av.z, av.w};
                float b_[4] = {bv.x, bv.y, bv.z, bv.w};
#pragma unroll
                for (int i = 0; i < 4; i++)
#pragma unroll
                    for (int j = 0; j < 4; j++) sacc[i][j] += a_[i] * b_[j];
            }
            __syncthreads();

#pragma unroll
            for (int i = 0; i < 4; i++)
#pragma unroll
                for (int j = 0; j < 4; j++) {
                    int m = r0 + (ty << 2) + i;
                    int n = n0 + (tx << 2) + j;
                    float dm = (m >= n) ? expf(-s * (float)(m - n)) : 0.f;
                    sT[(tx << 2) + j][(ty << 2) + i] = sacc[i][j] * dm;
                }
#pragma unroll
            for (int i = 0; i < 4; i++) {        // v tile (natural)
                int idx = t + 256 * i;
                int n = idx >> 4, c = (idx & 15) << 2;
                float4 v4 = load4(base + (long)(n0 + n) * QKVW + 2 * HDIM + c);
                *(float4*)&kvT[n][c] = v4;
            }
            __syncthreads();
#pragma unroll 8
            for (int nn = 0; nn < 64; nn++) {    // acc += S @ v
                float4 av = *(const float4*)&sT[nn][ty << 2];
                float4 bv = *(const float4*)&kvT[nn][tx << 2];
                float a_[4] = {av.x, av.y, av.z, av.w};
                float b_[4] = {bv.x, bv.y, bv.z, bv.w};
#pragma unroll
                for (int i = 0; i < 4; i++)
#pragma unroll
                    for (int j = 0; j < 4; j++) acc[i][j] += a_[i] * b_[j];
            }
        }

        float* hp = hidden + ((long)(b * BLK + r0 + (ty << 2))) * HIDDEN +
                    h * HDIM + (tx << 2);
#pragma unroll
        for (int i = 0; i < 4; i++) {
            float4 o = {acc[i][0], acc[i][1], acc[i][2], acc[i][3]};
            *(float4*)(hp + (long)i * HIDDEN) = o;
        }
    }
}

// ---------------------------------------------------------------------------
// RMSNorm over rows (in place). grid NTOK, 256 threads.
// ---------------------------------------------------------------------------
__global__ __launch_bounds__(256) void rmsnorm_rows(
    float* __restrict__ hidden, const float* __restrict__ w) {
    const int row = blockIdx.x, t = threadIdx.x;
    float* hp = hidden + (long)row * HIDDEN;
    float4 a = *(const float4*)(hp + (t << 2));
    float4 b = *(const float4*)(hp + 1024 + (t << 2));
    float ss = a.x * a.x + a.y * a.y + a.z * a.z + a.w * a.w +
               b.x * b.x + b.y * b.y + b.z * b.z + b.w * b.w;
#pragma unroll
    for (int off = 32; off > 0; off >>= 1) ss += __shfl_down(ss, off);
    __shared__ float red[4];
    if ((t & 63) == 0) red[t >> 6] = ss;
    __syncthreads();
    float tot = red[0] + red[1] + red[2] + red[3];
    float scale = rsqrtf(tot * (1.f / HIDDEN) + 1e-5f);
    float4 wa = *(const float4*)(w + (t << 2));
    float4 wb = *(const float4*)(w + 1024 + (t << 2));
    a.x *= scale * wa.x; a.y *= scale * wa.y; a.z *= scale * wa.z; a.w *= scale * wa.w;
    b.x *= scale * wb.x; b.y *= scale * wb.y; b.z *= scale * wb.z; b.w *= scale * wb.w;
    *(float4*)(hp + (t << 2)) = a;
    *(float4*)(hp + 1024 + (t << 2)) = b;
}

// ---------------------------------------------------------------------------
extern "C" void kernel_launch(void* const* d_in, const int* in_sizes, int n_in,
                              void* d_out, int out_size, void* d_ws, size_t ws_size,
                              hipStream_t stream) {
    (void)in_sizes; (void)n_in; (void)out_size; (void)ws_size;
    const float* hs   = (const float*)d_in[0];   // (8192, 2048)
    const float* kv0  = (const float*)d_in[1];   // (32, 64, 64)
    const float* Wqkv = (const float*)d_in[2];   // (6144, 2048)
    const float* Wg   = (const float*)d_in[3];   // (2048, 2048)
    const float* Wo   = (const float*)d_in[4];   // (2048, 2048)
    const float* nw   = (const float*)d_in[5];   // (2048,)
    float* out = (float*)d_out;

    // workspace (ushort elems): hs_h 16.78M | wqkv_h 12.58M | wg_h 4.19M |
    // wo_h 4.19M | qkv_h 50.33M (gated reuses) | cs fp32 4.19M  => 184 MiB
    ushort_t* hs_h   = (ushort_t*)d_ws;
    ushort_t* wqkv_h = hs_h + (size_t)NTOK * HIDDEN;
    ushort_t* wg_h   = wqkv_h + (size_t)QKVW * HIDDEN;
    ushort_t* wo_h   = wg_h + (size_t)HIDDEN * HIDDEN;
    ushort_t* qkv_h  = wo_h + (size_t)HIDDEN * HIDDEN;
    float*    cs     = (float*)(qkv_h + (size_t)NTOK * QKVW);
    ushort_t* gated  = qkv_h;                    // reuse after attention

    // fp32 -> bf16 converts
    cvt_bf16<<<(NTOK * HIDDEN / 8 + 255) / 256, 256, 0, stream>>>(
        hs, hs_h, NTOK * HIDDEN / 8);
    cvt_bf16<<<(QKVW * HIDDEN / 8 + 255) / 256, 256, 0, stream>>>(
        Wqkv, wqkv_h, QKVW * HIDDEN / 8);
    cvt_bf16<<<(HIDDEN * HIDDEN / 8 + 255) / 256, 256, 0, stream>>>(
        Wg, wg_h, HIDDEN * HIDDEN / 8);
    cvt_bf16<<<(HIDDEN * HIDDEN / 8 + 255) / 256, 256, 0, stream>>>(
        Wo, wo_h, HIDDEN * HIDDEN / 8);

    // 1. qkv = silu(hs @ Wqkv^T)   (bf16 out)
    gemm_bt_bf16<0, ushort_t><<<dim3(QKVW / 128, NTOK / 128), 256, 0, stream>>>(
        hs_h, wqkv_h, qkv_h, nullptr, NTOK, QKVW, HIDDEN);
    // 2-4. attention
    attn_contrib<ushort_t><<<dim3(NBLK, NHEAD), 256, 0, stream>>>(qkv_h, cs);
    attn_scan<<<NHEAD, 256, 0, stream>>>(kv0, cs, cs);
    attn_intra<ushort_t><<<dim3(NBLK, NHEAD), 256, 0, stream>>>(qkv_h, cs, out);
    // 5. RMSNorm in place on d_out
    rmsnorm_rows<<<NTOK, 256, 0, stream>>>(out, nw);
    // 6. gated = sigmoid(hs @ Wg^T) * normed   (bf16 out)
    gemm_bt_bf16<2, ushort_t><<<dim3(HIDDEN / 128, NTOK / 128), 256, 0, stream>>>(
        hs_h, wg_h, gated, out, NTOK, HIDDEN, HIDDEN);
    // 7. out = gated @ Wo^T
    gemm_bt_bf16<1, float><<<dim3(HIDDEN / 128, NTOK / 128), 256, 0, stream>>>(
        gated, wo_h, out, nullptr, NTOK, HIDDEN, HIDDEN);
}

// Round 4
// 774.591 us; speedup vs baseline: 5.6794x; 1.2709x over previous
//
#include <hip/hip_runtime.h>

// Problem constants (fixed by reference)
#define NTOK   8192
#define HIDDEN 2048
#define NHEAD  32
#define HDIM   64
#define BLK    256
#define NBLK   32          // NTOK / BLK
#define QKVW   6144        // 3 * HIDDEN

typedef unsigned short ushort_t;
typedef __attribute__((ext_vector_type(8))) short bf16x8;   // 8 bf16 = 4 VGPRs
typedef __attribute__((ext_vector_type(4))) float floatx4;  // MFMA C/D
typedef __attribute__((ext_vector_type(4))) unsigned short ushortx4;

#define MFMA16(a, b, c) __builtin_amdgcn_mfma_f32_16x16x32_bf16(a, b, c, 0, 0, 0)

// slope[h] = 2^(-0.25*(h+1)) * (1 - 0/79 + 1e-5)
__device__ __forceinline__ float head_slope(int h) {
    return exp2f(-0.25f * (float)(h + 1)) * 1.00001f;
}

__device__ __forceinline__ ushort_t f2bf(float x) {
    unsigned int u = __float_as_uint(x);
    unsigned int r = (u + 0x7FFFu + ((u >> 16) & 1u)) >> 16;   // RNE
    return (ushort_t)r;
}
__device__ __forceinline__ float bf2f(ushort_t x) {
    return __uint_as_float(((unsigned int)x) << 16);
}
__device__ __forceinline__ void store1(float* p, float v) { *p = v; }
__device__ __forceinline__ void store1(ushort_t* p, float v) { *p = f2bf(v); }

// async global->LDS, 16B per lane (lds dest = wave-uniform base + lane*16)
#define GLOAD_LDS16(g, l)                                              \
    __builtin_amdgcn_global_load_lds(                                  \
        (const __attribute__((address_space(1))) void*)(g),            \
        (__attribute__((address_space(3))) void*)(l), 16, 0, 0)

// ---------------------------------------------------------------------------
// fp32 -> bf16 convert, 8 elems/thread.
// ---------------------------------------------------------------------------
__global__ __launch_bounds__(256) void cvt_bf16(
    const float* __restrict__ in, ushort_t* __restrict__ out, int n8) {
    int i = blockIdx.x * 256 + threadIdx.x;
    if (i >= n8) return;
    long base = (long)i * 8;
    float4 a = *(const float4*)(in + base);
    float4 b = *(const float4*)(in + base + 4);
    ushort4 u0 = {f2bf(a.x), f2bf(a.y), f2bf(a.z), f2bf(a.w)};
    ushort4 u1 = {f2bf(b.x), f2bf(b.y), f2bf(b.z), f2bf(b.w)};
    *(ushort4*)(out + base) = u0;
    *(ushort4*)(out + base + 4) = u1;
}

// ---------------------------------------------------------------------------
// bf16 MFMA GEMM: C[M,N] = epi(A[M,K] @ B[N,K]^T), fp32 accumulate.
// 128x128 tile, BK=32. XOR-swizzled LDS chunks: staging lane fetches global
// chunk (lane&3)^((lane>>3)&3) so fragment reads land 2-way max (free).
// ---------------------------------------------------------------------------
template <int EPI, typename OutT>
__global__ __launch_bounds__(256) void gemm_bt_bf16(
    const ushort_t* __restrict__ A, const ushort_t* __restrict__ B,
    OutT* __restrict__ C, const float* __restrict__ Mul,
    int M, int Ncol, int K) {
    __shared__ ushort_t Al[128 * 32];   // [row][k-chunk perm], 64B rows
    __shared__ ushort_t Bl[128 * 32];

    const int t = threadIdx.x;
    const int wave = t >> 6, lane = t & 63;
    const int bm = blockIdx.y, bn = blockIdx.x;
    const int wm = (wave >> 1) * 64;
    const int wn = (wave & 1) * 64;

    // staging: row srow = lane>>2; fetch permuted chunk
    const int srow = lane >> 2;
    const int scol = ((lane & 3) ^ ((lane >> 3) & 3)) * 8;   // bf16 col
    const ushort_t* Ag0 = A + ((long)(bm * 128 + wave * 16 + srow)) * K + scol;
    const ushort_t* Ag1 = Ag0 + (long)64 * K;
    const ushort_t* Bg0 = B + ((long)(bn * 128 + wave * 16 + srow)) * K + scol;
    const ushort_t* Bg1 = Bg0 + (long)64 * K;
    ushort_t* Al0 = &Al[(wave * 16) * 32];
    ushort_t* Al1 = &Al[(wave * 16 + 64) * 32];
    ushort_t* Bl0 = &Bl[(wave * 16) * 32];
    ushort_t* Bl1 = &Bl[(wave * 16 + 64) * 32];

    // fragment read: row fm, data chunk fq -> position fq ^ ((fm>>1)&3)
    const int fm = lane & 15;
    const int fq = lane >> 4;
    const int fkp = (fq ^ ((fm >> 1) & 3)) * 8;

    floatx4 acc[4][4];
#pragma unroll
    for (int i = 0; i < 4; i++)
#pragma unroll
        for (int j = 0; j < 4; j++) acc[i][j] = (floatx4){0.f, 0.f, 0.f, 0.f};

    for (int k0 = 0; k0 < K; k0 += 32) {
        GLOAD_LDS16(Ag0 + k0, Al0);
        GLOAD_LDS16(Ag1 + k0, Al1);
        GLOAD_LDS16(Bg0 + k0, Bl0);
        GLOAD_LDS16(Bg1 + k0, Bl1);
        __syncthreads();

        bf16x8 af[4], bf[4];
#pragma unroll
        for (int mt = 0; mt < 4; mt++)
            af[mt] = *(const bf16x8*)&Al[(wm + mt * 16 + fm) * 32 + fkp];
#pragma unroll
        for (int nt = 0; nt < 4; nt++)
            bf[nt] = *(const bf16x8*)&Bl[(wn + nt * 16 + fm) * 32 + fkp];
#pragma unroll
        for (int mt = 0; mt < 4; mt++)
#pragma unroll
            for (int nt = 0; nt < 4; nt++)
                acc[mt][nt] = MFMA16(af[mt], bf[nt], acc[mt][nt]);
        __syncthreads();
    }

    const int cq = lane >> 4;
#pragma unroll
    for (int mt = 0; mt < 4; mt++)
#pragma unroll
        for (int nt = 0; nt < 4; nt++) {
            long col = (long)bn * 128 + wn + nt * 16 + fm;
#pragma unroll
            for (int r = 0; r < 4; r++) {
                long row = (long)bm * 128 + wm + mt * 16 + cq * 4 + r;
                long idx = row * Ncol + col;
                float x = acc[mt][nt][r];
                float o;
                if (EPI == 0)      o = x / (1.f + expf(-x));          // silu
                else if (EPI == 1) o = x;                             // plain
                else               o = Mul[idx] / (1.f + expf(-x));   // gate
                store1(C + idx, o);
            }
        }
}

// ---------------------------------------------------------------------------
// MFMA contrib: contrib[h][b][d][e] = sum_n kd[n]*k[n][d]*v[n][e].
// Wave w owns d rows w*16..+16, loops 4 token-tiles of 64 (K accumulate).
// ---------------------------------------------------------------------------
__global__ __launch_bounds__(256) void attn_contrib_mfma(
    const ushort_t* __restrict__ qkv, float* __restrict__ contrib) {
    const int b = blockIdx.x, h = blockIdx.y;
    const float s = head_slope(h);
    __shared__ ushort_t kdT[64][72];   // [d][n]  k*kdecay, rows 144B
    __shared__ ushort_t vT[64][72];    // [e][n]
    const int t = threadIdx.x, wave = t >> 6, lane = t & 63;
    const int fm = lane & 15, quad = lane >> 4;
    const ushort_t* base = qkv + (long)(b * BLK) * QKVW + h * (3 * HDIM);

    floatx4 acc[4];
#pragma unroll
    for (int e = 0; e < 4; e++) acc[e] = (floatx4){0.f, 0.f, 0.f, 0.f};

    const int sn = t & 63;             // token within tile
    const int sc0 = t >> 6;            // chunk 0..3 (+4)

    for (int tt = 0; tt < 4; tt++) {
        __syncthreads();
        int tok = tt * 64 + sn;
        float kd = expf(-s * (float)(BLK - 1 - tok));
#pragma unroll
        for (int cc = 0; cc < 2; cc++) {
            int c = sc0 + cc * 4;
            bf16x8 k8 = *(const bf16x8*)(base + (long)tok * QKVW + HDIM + c * 8);
            bf16x8 v8 = *(const bf16x8*)(base + (long)tok * QKVW + 2 * HDIM + c * 8);
#pragma unroll
            for (int j = 0; j < 8; j++) {
                kdT[c * 8 + j][sn] = f2bf(bf2f((ushort_t)k8[j]) * kd);
                vT[c * 8 + j][sn]  = (ushort_t)v8[j];
            }
        }
        __syncthreads();
#pragma unroll
        for (int kh = 0; kh < 2; kh++) {
            bf16x8 a = *(const bf16x8*)&kdT[wave * 16 + fm][kh * 32 + quad * 8];
#pragma unroll
            for (int e = 0; e < 4; e++) {
                bf16x8 bb = *(const bf16x8*)&vT[e * 16 + fm][kh * 32 + quad * 8];
                acc[e] = MFMA16(a, bb, acc[e]);
            }
        }
    }
    float* outp = contrib + ((long)(h * NBLK + b)) * 4096;
#pragma unroll
    for (int e = 0; e < 4; e++)
#pragma unroll
        for (int r = 0; r < 4; r++) {
            int d = wave * 16 + quad * 4 + r;
            outp[d * 64 + e * 16 + fm] = acc[e][r];
        }
}

// ---------------------------------------------------------------------------
// Sequential decay scan over blocks (in-place safe).
// ---------------------------------------------------------------------------
__global__ __launch_bounds__(256) void attn_scan(
    const float* __restrict__ kv0, const float* __restrict__ contrib,
    float* __restrict__ states) {
    const int h = blockIdx.x, t = threadIdx.x;
    const float s  = head_slope(h);
    const float bd = expf(-s * (float)BLK);
    float st[16], c[16];
    const float* kvp = kv0 + (long)h * 4096;
#pragma unroll
    for (int i = 0; i < 16; i++) st[i] = kvp[t + 256 * i];
    for (int b = 0; b < NBLK; b++) {
        const float* cp = contrib + ((long)(h * NBLK + b)) * 4096;
        float* sp = states + ((long)(h * NBLK + b)) * 4096;
#pragma unroll
        for (int i = 0; i < 16; i++) c[i] = cp[t + 256 * i];
#pragma unroll
        for (int i = 0; i < 16; i++) sp[t + 256 * i] = st[i];
#pragma unroll
        for (int i = 0; i < 16; i++) st[i] = bd * st[i] + c[i];
    }
}

// ---------------------------------------------------------------------------
// MFMA attention core per (h,b):
//   out = diag(qdec)*(q @ state) + ((q@k^T) .* decay) @ v
// Wave w owns q rows w*64..+64. S computed transposed (A=k, B=q) so the
// decayed tile stores to Sw[m][n] as ushort4 rows; then intra A=Sw, B=vT.
// ---------------------------------------------------------------------------
__global__ __launch_bounds__(256) void attn_core_mfma(
    const ushort_t* __restrict__ qkv, const float* __restrict__ states,
    float* __restrict__ hidden) {
    const int b = blockIdx.x, h = blockIdx.y;
    const float s = head_slope(h);
    __shared__ ushort_t Sw[4][64][72];   // per-wave S tile; Sw[0] = stT first
    __shared__ ushort_t kS[64 * 64];     // k tile [n][d], 128B rows, swizzled
    __shared__ ushort_t vT[64][72];      // v tile [e][n]
    __shared__ float dtab[257];          // exp(-s*delta)
    __shared__ float etab[64];           // exp(+s*j)
    const int t = threadIdx.x, wave = t >> 6, lane = t & 63;
    const int fm = lane & 15, quad = lane >> 4;
    const ushort_t* base = qkv + (long)(b * BLK) * QKVW + h * (3 * HDIM);

    dtab[t] = expf(-s * (float)t);
    if (t == 0) dtab[256] = expf(-s * 256.f);
    if (t < 64) etab[t] = expf(s * (float)t);

    {   // stT = Sw[0]: [e][d] <- states (bf16)
        const float* sp = states + ((long)(h * NBLK + b)) * 4096;
#pragma unroll
        for (int i = 0; i < 4; i++) {
            int idx = t + 256 * i;
            int d = idx >> 4, e4 = (idx & 15) * 4;
            float4 st4 = *(const float4*)(sp + d * 64 + e4);
            Sw[0][e4 + 0][d] = f2bf(st4.x);
            Sw[0][e4 + 1][d] = f2bf(st4.y);
            Sw[0][e4 + 2][d] = f2bf(st4.z);
            Sw[0][e4 + 3][d] = f2bf(st4.w);
        }
    }

    // q fragments from global (read once)
    bf16x8 aq[4][2];
#pragma unroll
    for (int mt = 0; mt < 4; mt++)
#pragma unroll
        for (int kh = 0; kh < 2; kh++)
            aq[mt][kh] = *(const bf16x8*)(base +
                (long)(wave * 64 + mt * 16 + fm) * QKVW + kh * 32 + quad * 8);

    __syncthreads();

    // inter = q @ state, then row-scale by qdecay
    floatx4 acc[4][4];
#pragma unroll
    for (int i = 0; i < 4; i++)
#pragma unroll
        for (int j = 0; j < 4; j++) acc[i][j] = (floatx4){0.f, 0.f, 0.f, 0.f};
#pragma unroll
    for (int kh = 0; kh < 2; kh++)
#pragma unroll
        for (int et = 0; et < 4; et++) {
            bf16x8 bst = *(const bf16x8*)&Sw[0][et * 16 + fm][kh * 32 + quad * 8];
#pragma unroll
            for (int mt = 0; mt < 4; mt++)
                acc[mt][et] = MFMA16(aq[mt][kh], bst, acc[mt][et]);
        }
#pragma unroll
    for (int mt = 0; mt < 4; mt++)
#pragma unroll
        for (int r = 0; r < 4; r++) {
            float qd = dtab[wave * 64 + mt * 16 + quad * 4 + r + 1];
#pragma unroll
            for (int et = 0; et < 4; et++) acc[mt][et][r] *= qd;
        }

    // intra over k-tiles (uniform loop; wave computes only nt <= wave)
    const int sn = t & 63, sc0 = t >> 6;
    for (int nt = 0; nt < 4; nt++) {
        __syncthreads();   // prior reads of kS/vT/stT done before restage
        // stage kS via global_load_lds, chunk-swizzled (pos p holds p^(n&7))
#pragma unroll
        for (int i = 0; i < 2; i++) {
            int row = i * 32 + wave * 8 + (lane >> 3);
            const ushort_t* g = base + (long)(nt * 64 + row) * QKVW + HDIM +
                                (((lane & 7) ^ (lane >> 3)) * 8);
            GLOAD_LDS16(g, &kS[(i * 32 + wave * 8) * 64]);
        }
        // stage vT tile [e][n]
#pragma unroll
        for (int cc = 0; cc < 2; cc++) {
            int c = sc0 + cc * 4;
            bf16x8 v8 = *(const bf16x8*)(base + (long)(nt * 64 + sn) * QKVW +
                                         2 * HDIM + c * 8);
#pragma unroll
            for (int j = 0; j < 8; j++) vT[c * 8 + j][sn] = (ushort_t)v8[j];
        }
        __syncthreads();

        if (nt <= wave) {
            // S^T = k @ q^T : C row = n, col = m
            floatx4 sacc[4][4];
#pragma unroll
            for (int i = 0; i < 4; i++)
#pragma unroll
                for (int j = 0; j < 4; j++) sacc[i][j] = (floatx4){0.f, 0.f, 0.f, 0.f};
#pragma unroll
            for (int kh = 0; kh < 2; kh++) {
                bf16x8 ak[4];
#pragma unroll
                for (int snt = 0; snt < 4; snt++) {
                    int n = snt * 16 + fm;
                    int pos = (kh * 4 + quad) ^ (n & 7);
                    ak[snt] = *(const bf16x8*)&kS[n * 64 + pos * 8];
                }
#pragma unroll
                for (int snt = 0; snt < 4; snt++)
#pragma unroll
                    for (int smt = 0; smt < 4; smt++)
                        sacc[snt][smt] = MFMA16(ak[snt], aq[smt][kh], sacc[snt][smt]);
            }
            // decay + mask + bf16, store Sw[wave][m][n] (ushort4 rows)
#pragma unroll
            for (int snt = 0; snt < 4; snt++)
#pragma unroll
                for (int smt = 0; smt < 4; smt++) {
                    int mloc = smt * 16 + fm;              // 0..63 in wave rows
                    float rf = dtab[wave * 64 + mloc - nt * 64];
                    ushortx4 o;
#pragma unroll
                    for (int r = 0; r < 4; r++) {
                        int nloc = snt * 16 + quad * 4 + r;
                        float v = sacc[snt][smt][r] * rf * etab[nloc];
                        if (nt == wave && mloc < nloc) v = 0.f;
                        o[r] = f2bf(v);
                    }
                    *(ushortx4*)&Sw[wave][mloc][snt * 16 + quad * 4] = o;
                }
            // intra: acc += S @ v  (A = Sw rows m, B = vT rows e)
#pragma unroll
            for (int kh = 0; kh < 2; kh++) {
                bf16x8 as[4];
#pragma unroll
                for (int mt = 0; mt < 4; mt++)
                    as[mt] = *(const bf16x8*)&Sw[wave][mt * 16 + fm][kh * 32 + quad * 8];
#pragma unroll
                for (int et = 0; et < 4; et++) {
                    bf16x8 bv = *(const bf16x8*)&vT[et * 16 + fm][kh * 32 + quad * 8];
#pragma unroll
                    for (int mt = 0; mt < 4; mt++)
                        acc[mt][et] = MFMA16(as[mt], bv, acc[mt][et]);
                }
            }
        }
    }

    // write hidden[token][h*64+e] (coalesced 64B per quad)
#pragma unroll
    for (int mt = 0; mt < 4; mt++)
#pragma unroll
        for (int r = 0; r < 4; r++) {
            long tok = (long)b * BLK + wave * 64 + mt * 16 + quad * 4 + r;
            float* hp = hidden + tok * HIDDEN + h * HDIM;
#pragma unroll
            for (int et = 0; et < 4; et++)
                hp[et * 16 + fm] = acc[mt][et][r];
        }
}

// ---------------------------------------------------------------------------
// RMSNorm over rows (in place). grid NTOK, 256 threads.
// ---------------------------------------------------------------------------
__global__ __launch_bounds__(256) void rmsnorm_rows(
    float* __restrict__ hidden, const float* __restrict__ w) {
    const int row = blockIdx.x, t = threadIdx.x;
    float* hp = hidden + (long)row * HIDDEN;
    float4 a = *(const float4*)(hp + (t << 2));
    float4 b = *(const float4*)(hp + 1024 + (t << 2));
    float ss = a.x * a.x + a.y * a.y + a.z * a.z + a.w * a.w +
               b.x * b.x + b.y * b.y + b.z * b.z + b.w * b.w;
#pragma unroll
    for (int off = 32; off > 0; off >>= 1) ss += __shfl_down(ss, off);
    __shared__ float red[4];
    if ((t & 63) == 0) red[t >> 6] = ss;
    __syncthreads();
    float tot = red[0] + red[1] + red[2] + red[3];
    float scale = rsqrtf(tot * (1.f / HIDDEN) + 1e-5f);
    float4 wa = *(const float4*)(w + (t << 2));
    float4 wb = *(const float4*)(w + 1024 + (t << 2));
    a.x *= scale * wa.x; a.y *= scale * wa.y; a.z *= scale * wa.z; a.w *= scale * wa.w;
    b.x *= scale * wb.x; b.y *= scale * wb.y; b.z *= scale * wb.z; b.w *= scale * wb.w;
    *(float4*)(hp + (t << 2)) = a;
    *(float4*)(hp + 1024 + (t << 2)) = b;
}

// ---------------------------------------------------------------------------
extern "C" void kernel_launch(void* const* d_in, const int* in_sizes, int n_in,
                              void* d_out, int out_size, void* d_ws, size_t ws_size,
                              hipStream_t stream) {
    (void)in_sizes; (void)n_in; (void)out_size; (void)ws_size;
    const float* hs   = (const float*)d_in[0];
    const float* kv0  = (const float*)d_in[1];
    const float* Wqkv = (const float*)d_in[2];
    const float* Wg   = (const float*)d_in[3];
    const float* Wo   = (const float*)d_in[4];
    const float* nw   = (const float*)d_in[5];
    float* out = (float*)d_out;

    ushort_t* hs_h   = (ushort_t*)d_ws;
    ushort_t* wqkv_h = hs_h + (size_t)NTOK * HIDDEN;
    ushort_t* wg_h   = wqkv_h + (size_t)QKVW * HIDDEN;
    ushort_t* wo_h   = wg_h + (size_t)HIDDEN * HIDDEN;
    ushort_t* qkv_h  = wo_h + (size_t)HIDDEN * HIDDEN;
    float*    cs     = (float*)(qkv_h + (size_t)NTOK * QKVW);
    ushort_t* gated  = qkv_h;                    // reuse after attention

    cvt_bf16<<<(NTOK * HIDDEN / 8 + 255) / 256, 256, 0, stream>>>(
        hs, hs_h, NTOK * HIDDEN / 8);
    cvt_bf16<<<(QKVW * HIDDEN / 8 + 255) / 256, 256, 0, stream>>>(
        Wqkv, wqkv_h, QKVW * HIDDEN / 8);
    cvt_bf16<<<(HIDDEN * HIDDEN / 8 + 255) / 256, 256, 0, stream>>>(
        Wg, wg_h, HIDDEN * HIDDEN / 8);
    cvt_bf16<<<(HIDDEN * HIDDEN / 8 + 255) / 256, 256, 0, stream>>>(
        Wo, wo_h, HIDDEN * HIDDEN / 8);

    gemm_bt_bf16<0, ushort_t><<<dim3(QKVW / 128, NTOK / 128), 256, 0, stream>>>(
        hs_h, wqkv_h, qkv_h, nullptr, NTOK, QKVW, HIDDEN);
    attn_contrib_mfma<<<dim3(NBLK, NHEAD), 256, 0, stream>>>(qkv_h, cs);
    attn_scan<<<NHEAD, 256, 0, stream>>>(kv0, cs, cs);
    attn_core_mfma<<<dim3(NBLK, NHEAD), 256, 0, stream>>>(qkv_h, cs, out);
    rmsnorm_rows<<<NTOK, 256, 0, stream>>>(out, nw);
    gemm_bt_bf16<2, ushort_t><<<dim3(HIDDEN / 128, NTOK / 128), 256, 0, stream>>>(
        hs_h, wg_h, gated, out, NTOK, HIDDEN, HIDDEN);
    gemm_bt_bf16<1, float><<<dim3(HIDDEN / 128, NTOK / 128), 256, 0, stream>>>(
        gated, wo_h, out, nullptr, NTOK, HIDDEN, HIDDEN);
}